// Round 3
// baseline (236.491 us; speedup 1.0000x reference)
//
#include <hip/hip_runtime.h>
#include <hip/hip_bf16.h>
#include <stdint.h>

#define B_N 2
#define S_N 2048
#define D_N 1024
#define H_N 16

using bf8   = __attribute__((ext_vector_type(8))) short;   // 8 bf16 (4 VGPRs)
using f32x4 = __attribute__((ext_vector_type(4))) float;

static __device__ __forceinline__ ushort f2b(float f) {
  uint32_t u = __builtin_bit_cast(uint32_t, f);
  u += 0x7fffu + ((u >> 16) & 1u);     // RNE
  return (ushort)(u >> 16);
}

typedef __attribute__((address_space(1))) const uint32_t GU32;
typedef __attribute__((address_space(3))) uint32_t LU32;
static __device__ __forceinline__ void gload16(const void* g, void* l) {
  __builtin_amdgcn_global_load_lds((GU32*)g, (LU32*)l, 16, 0, 0);
}

// ---------------- f32 -> bf16 converts (fused) ----------------
__global__ __launch_bounds__(256) void cvt3_kernel(const float* __restrict__ a, const float* __restrict__ b,
                                                   const float* __restrict__ c, ushort* __restrict__ oa,
                                                   ushort* __restrict__ ob, ushort* __restrict__ oc) {
  const float* s; ushort* d;
  if (blockIdx.y == 0) { s = a; d = oa; }
  else if (blockIdx.y == 1) { s = b; d = ob; }
  else { s = c; d = oc; }
  int i = (blockIdx.x * 256 + threadIdx.x) * 4;
  float4 v = *(const float4*)(s + i);
  ushort4 o;
  o.x = f2b(v.x); o.y = f2b(v.y); o.z = f2b(v.z); o.w = f2b(v.w);
  *(ushort4*)(d + i) = o;
}

__global__ __launch_bounds__(256) void cvt4_kernel(const float* __restrict__ a, const float* __restrict__ b,
                                                   const float* __restrict__ c, const float* __restrict__ e,
                                                   ushort* __restrict__ oa, ushort* __restrict__ ob,
                                                   ushort* __restrict__ oc, ushort* __restrict__ oe) {
  const float* s; ushort* d;
  if (blockIdx.y == 0) { s = a; d = oa; }
  else if (blockIdx.y == 1) { s = b; d = ob; }
  else if (blockIdx.y == 2) { s = c; d = oc; }
  else { s = e; d = oe; }
  int i = (blockIdx.x * 256 + threadIdx.x) * 4;
  float4 v = *(const float4*)(s + i);
  ushort4 o;
  o.x = f2b(v.x); o.y = f2b(v.y); o.z = f2b(v.z); o.w = f2b(v.w);
  *(ushort4*)(d + i) = o;
}

// ---------------- structural-bias precompute ----------------
__global__ __launch_bounds__(256) void pack_codes_kernel(
    const int* __restrict__ f, const int* __restrict__ e, const int* __restrict__ ti,
    const int* __restrict__ tt, const int* __restrict__ ed, const int* __restrict__ ro,
    uint32_t* __restrict__ codes, int n) {
  int i = blockIdx.x * 256 + threadIdx.x;
  if (i >= n) return;
  uint32_t c = ((uint32_t)f[i] & 31u) | (((uint32_t)e[i] & 63u) << 5) |
               (((uint32_t)ti[i] & 127u) << 11) | (((uint32_t)tt[i] & 7u) << 18) |
               (((uint32_t)ro[i] & 7u) << 21) |
               ((ed[i] != 0) ? (1u << 24) : 0u) | ((f[i] == 0) ? (1u << 25) : 0u);
  codes[i] = c;
}

static __device__ __forceinline__ float bias_val(uint32_t a, uint32_t b) {
  uint32_t x = a ^ b;
  uint32_t o = a | b;
  float v = (o & 0x1000000u) ? 1.5f : 0.0f;   // has_edge
  v += (x & 0x1Fu)     ? 0.0f : 1.0f;          // field
  v += (x & 0x7E0u)    ? 0.0f : 1.0f;          // entity
  v += (x & 0x3F800u)  ? 0.0f : 0.5f;          // time
  v += (x & 0x1C0000u) ? 0.0f : 0.3f;          // token_type
  v += (x & 0xE00000u) ? 0.0f : 0.5f;          // role
  return (o & 0x2000000u) ? -30000.f : v;      // pad -> big negative
}

// BM[b][i][j] f32, 8 elements per thread
__global__ __launch_bounds__(256) void bias_build(const uint32_t* __restrict__ codes,
                                                  float* __restrict__ BM) {
  int t = blockIdx.x * 256 + threadIdx.x;      // 0 .. B*S*S/8-1
  int j8 = (t & 255) * 8;                      // S/8 = 256
  int i  = (t >> 8) & 2047;
  int b  = t >> 19;                            // S*S/8 = 2^19
  uint32_t cq = codes[b * S_N + i];
  uint4 c0 = *(const uint4*)(codes + b * S_N + j8);
  uint4 c1 = *(const uint4*)(codes + b * S_N + j8 + 4);
  uint32_t cj[8] = {c0.x, c0.y, c0.z, c0.w, c1.x, c1.y, c1.z, c1.w};
  float o[8];
#pragma unroll
  for (int p = 0; p < 8; ++p) o[p] = bias_val(cq, cj[p]);
  *(float4*)(BM + (size_t)t * 8)     = *(const float4*)(o);
  *(float4*)(BM + (size_t)t * 8 + 4) = *(const float4*)(o + 4);
}

// ---------------- GEMM core: C[M,N] = A[M,K] @ W[N,K]^T + bias ----------------
// 128x128 tile, BK=32, 4 waves (2x2), 4x4 16x16 frags per wave, global_load_lds staging.
// MODE 0: bf16 scatter to [B,H,S,64]; MODE 1: f32 [M,N]; MODE 2: bf16 scatter-T to [B,H,64,S]
template <int MODE>
static __device__ __forceinline__ void gemm_core(ushort* As, ushort* Bs,
    const ushort* __restrict__ A, const ushort* __restrict__ W, const float* __restrict__ bias,
    void* __restrict__ out, float scale) {
  const int tid = threadIdx.x, lane = tid & 63, wid = tid >> 6;
  const int g = lane >> 4, c = lane & 15;
  const int wm = wid >> 1, wn = wid & 1;
  const int m0 = blockIdx.y * 128, n0 = blockIdx.x * 128;

  f32x4 acc[4][4];
#pragma unroll
  for (int i = 0; i < 4; ++i)
#pragma unroll
    for (int j = 0; j < 4; ++j) acc[i][j] = (f32x4){0.f, 0.f, 0.f, 0.f};

  for (int k0 = 0; k0 < D_N; k0 += 32) {
#pragma unroll
    for (int j = 0; j < 2; ++j) {
      int idx = tid + j * 256;                  // 0..511
      int row = idx >> 2, c8 = (idx & 3) * 8;
      gload16(A + (size_t)(m0 + row) * D_N + k0 + c8, As + idx * 8);
      gload16(W + (size_t)(n0 + row) * D_N + k0 + c8, Bs + idx * 8);
    }
    __syncthreads();
    bf8 af[4], bw[4];
#pragma unroll
    for (int mi = 0; mi < 4; ++mi) af[mi] = *(const bf8*)(As + (wm * 64 + mi * 16 + c) * 32 + g * 8);
#pragma unroll
    for (int ni = 0; ni < 4; ++ni) bw[ni] = *(const bf8*)(Bs + (wn * 64 + ni * 16 + c) * 32 + g * 8);
#pragma unroll
    for (int mi = 0; mi < 4; ++mi)
#pragma unroll
      for (int ni = 0; ni < 4; ++ni)
        acc[mi][ni] = __builtin_amdgcn_mfma_f32_16x16x32_bf16(af[mi], bw[ni], acc[mi][ni], 0, 0, 0);
    __syncthreads();
  }

#pragma unroll
  for (int mi = 0; mi < 4; ++mi)
#pragma unroll
    for (int ni = 0; ni < 4; ++ni) {
      int ncol = n0 + wn * 64 + ni * 16 + c;
      float bv = bias[ncol];
      int hh = ncol >> 6, dd = ncol & 63;
      if (MODE == 2) {
        int mb = m0 + wm * 64 + mi * 16 + g * 4;
        int bb = mb >> 11, s = mb & 2047;
        ushort4 o4;
        o4.x = f2b((acc[mi][ni][0] + bv) * scale);
        o4.y = f2b((acc[mi][ni][1] + bv) * scale);
        o4.z = f2b((acc[mi][ni][2] + bv) * scale);
        o4.w = f2b((acc[mi][ni][3] + bv) * scale);
        *(ushort4*)((ushort*)out + (((size_t)bb * H_N + hh) * 64 + dd) * S_N + s) = o4;
      } else {
#pragma unroll
        for (int r = 0; r < 4; ++r) {
          int m = m0 + wm * 64 + mi * 16 + g * 4 + r;
          float v = (acc[mi][ni][r] + bv) * scale;
          if (MODE == 0) {
            int bb = m >> 11, s = m & 2047;
            ((ushort*)out)[(((size_t)bb * H_N + hh) * S_N + s) * 64 + dd] = f2b(v);
          } else {
            ((float*)out)[(size_t)m * D_N + ncol] = v;
          }
        }
      }
    }
}

__global__ __launch_bounds__(256) void gemm_qkv(
    const ushort* __restrict__ Xq, const ushort* __restrict__ Xk, const ushort* __restrict__ Xv,
    const ushort* __restrict__ Wq, const ushort* __restrict__ Wk, const ushort* __restrict__ Wv,
    const float* __restrict__ bq, const float* __restrict__ bk, const float* __restrict__ bv,
    ushort* __restrict__ Qo, ushort* __restrict__ Ko, ushort* __restrict__ Vo) {
  __shared__ __align__(16) ushort As[128 * 32];
  __shared__ __align__(16) ushort Bs[128 * 32];
  if (blockIdx.z == 0)      gemm_core<0>(As, Bs, Xq, Wq, bq, Qo, 0.125f);
  else if (blockIdx.z == 1) gemm_core<0>(As, Bs, Xk, Wk, bk, Ko, 1.0f);
  else                      gemm_core<2>(As, Bs, Xv, Wv, bv, Vo, 1.0f);
}

__global__ __launch_bounds__(256) void gemm_o(const ushort* __restrict__ A, const ushort* __restrict__ W,
                                              const float* __restrict__ bias, float* __restrict__ out) {
  __shared__ __align__(16) ushort As[128 * 32];
  __shared__ __align__(16) ushort Bs[128 * 32];
  gemm_core<1>(As, Bs, A, W, bias, out, 1.0f);
}

// ---------------- flash attention: 2-phase pipeline, counted vmcnt ----------------
// grid (S/64, B*H), 256 thr (4 waves x 16 q rows). Q pre-scaled by 0.125.
// K/V double-buffered via global_load_lds (pre-swizzled source); bias f32 direct
// global->reg, prefetched one tile ahead (rides in the vmcnt(16) allowance).
__global__ __launch_bounds__(256) void attn_kernel(const ushort* __restrict__ Qw, const ushort* __restrict__ Kw,
                                                   const ushort* __restrict__ VT, const float* __restrict__ BMf,
                                                   ushort* __restrict__ AO) {
  __shared__ __align__(16) ushort Ks[2][64 * 64];
  __shared__ __align__(16) ushort Vs[2][64 * 64];
  __shared__ __align__(16) ushort Ps[4][16 * 64];
  const int tid = threadIdx.x, lane = tid & 63, wid = tid >> 6;
  const int g = lane >> 4, c = lane & 15;
  const int bh = blockIdx.y, b = bh >> 4;
  const int q0 = blockIdx.x * 64;

  const ushort* Kbase = Kw + (size_t)bh * (S_N * 64);
  const ushort* Vbase = VT + (size_t)bh * (64 * S_N);
  const float*  Bbase = BMf + ((size_t)b * S_N + q0 + wid * 16 + g * 4) * S_N + c;

  bf8 aq[2];
  {
    const ushort* qp = Qw + ((size_t)bh * S_N + q0 + wid * 16 + c) * 64;
    aq[0] = *(const bf8*)(qp + g * 8);
    aq[1] = *(const bf8*)(qp + 32 + g * 8);
  }

  float mr[4], lr[4];
  f32x4 o[4];
#pragma unroll
  for (int r = 0; r < 4; ++r) { mr[r] = -1e30f; lr[r] = 0.f; }
#pragma unroll
  for (int t = 0; t < 4; ++t) o[t] = (f32x4){0.f, 0.f, 0.f, 0.f};

  auto STAGE = [&](int bufi, int kv0) {
#pragma unroll
    for (int j = 0; j < 2; ++j) {
      int idx = tid + j * 256;
      int row = idx >> 3, sl = ((idx & 7) ^ (row & 7)) * 8;
      gload16(Kbase + (size_t)(kv0 + row) * 64 + sl, &Ks[bufi][idx * 8]);
      gload16(Vbase + (size_t)row * S_N + kv0 + sl, &Vs[bufi][idx * 8]);
    }
  };
  auto BLOAD = [&](float* bn, int kv0) {
#pragma unroll
    for (int t = 0; t < 4; ++t)
#pragma unroll
      for (int r = 0; r < 4; ++r)
        bn[t * 4 + r] = Bbase[(size_t)r * S_N + kv0 + t * 16];
  };
  auto TILE = [&](int bufi, const float* bc) {
    f32x4 s[4];
#pragma unroll
    for (int t = 0; t < 4; ++t)
      s[t] = (f32x4){bc[t * 4 + 0], bc[t * 4 + 1], bc[t * 4 + 2], bc[t * 4 + 3]};
#pragma unroll
    for (int t = 0; t < 4; ++t) {
      int row = t * 16 + c;
#pragma unroll
      for (int kk = 0; kk < 2; ++kk) {
        bf8 kb = *(const bf8*)(&Ks[bufi][row * 64 + (((kk * 4 + g) ^ (row & 7)) * 8)]);
        s[t] = __builtin_amdgcn_mfma_f32_16x16x32_bf16(aq[kk], kb, s[t], 0, 0, 0);
      }
    }
    float mn[4], sc[4];
#pragma unroll
    for (int r = 0; r < 4; ++r) {
      float v = fmaxf(fmaxf(s[0][r], s[1][r]), fmaxf(s[2][r], s[3][r]));
      v = fmaxf(v, __shfl_xor(v, 1));
      v = fmaxf(v, __shfl_xor(v, 2));
      v = fmaxf(v, __shfl_xor(v, 4));
      v = fmaxf(v, __shfl_xor(v, 8));
      mn[r] = fmaxf(mr[r], v);
      sc[r] = __expf(mr[r] - mn[r]);
      mr[r] = mn[r];
    }
#pragma unroll
    for (int r = 0; r < 4; ++r) {
      float a0 = 0.f;
#pragma unroll
      for (int t = 0; t < 4; ++t) { s[t][r] = __expf(s[t][r] - mn[r]); a0 += s[t][r]; }
      a0 += __shfl_xor(a0, 1);
      a0 += __shfl_xor(a0, 2);
      a0 += __shfl_xor(a0, 4);
      a0 += __shfl_xor(a0, 8);
      lr[r] = lr[r] * sc[r] + a0;
#pragma unroll
      for (int t = 0; t < 4; ++t) o[t][r] *= sc[r];
    }
    ushort* P = &Ps[wid][0];
#pragma unroll
    for (int t = 0; t < 4; ++t)
#pragma unroll
      for (int r = 0; r < 4; ++r) {
        uint32_t pk;
        asm("v_cvt_pk_bf16_f32 %0, %1, %2" : "=v"(pk) : "v"(s[t][r]), "v"(s[t][r]));
        int row = g * 4 + r, col = t * 16 + c;
        P[(row * 128 + ((col * 2) ^ ((row & 7) << 4))) >> 1] = (ushort)pk;
      }
    bf8 pa[2];
#pragma unroll
    for (int kk = 0; kk < 2; ++kk)
      pa[kk] = *(const bf8*)((const char*)P + c * 128 + (((kk * 4 + g) ^ (c & 7)) * 16));
#pragma unroll
    for (int t = 0; t < 4; ++t) {
      int row = t * 16 + c;
#pragma unroll
      for (int kk = 0; kk < 2; ++kk) {
        bf8 vb = *(const bf8*)(&Vs[bufi][row * 64 + (((kk * 4 + g) ^ (row & 7)) * 8)]);
        o[t] = __builtin_amdgcn_mfma_f32_16x16x32_bf16(pa[kk], vb, o[t], 0, 0, 0);
      }
    }
  };

  float bA[16], bB[16];
  STAGE(0, 0);
  BLOAD(bA, 0);
#pragma unroll 1
  for (int kv0 = 0; kv0 < S_N; kv0 += 128) {
    // ---- tile kv0 (buf 0) ----
    asm volatile("s_waitcnt vmcnt(16)" ::: "memory");  // STAGE(buf0) done; bias prefetch may fly
    __builtin_amdgcn_s_barrier();
    __builtin_amdgcn_sched_barrier(0);
    if (kv0 + 64 < S_N) { STAGE(1, kv0 + 64); BLOAD(bB, kv0 + 64); }
    TILE(0, bA);
    // ---- tile kv0+64 (buf 1) ----
    asm volatile("s_waitcnt vmcnt(16)" ::: "memory");
    __builtin_amdgcn_s_barrier();
    __builtin_amdgcn_sched_barrier(0);
    if (kv0 + 128 < S_N) { STAGE(0, kv0 + 128); BLOAD(bA, kv0 + 128); }
    TILE(1, bB);
  }

  float inv[4];
#pragma unroll
  for (int r = 0; r < 4; ++r) inv[r] = __builtin_amdgcn_rcpf(lr[r]);
#pragma unroll
  for (int t = 0; t < 4; ++t) {
    int ncol = (bh & 15) * 64 + t * 16 + c;
#pragma unroll
    for (int r = 0; r < 4; ++r) {
      int qrow = q0 + wid * 16 + g * 4 + r;
      AO[((size_t)b * S_N + qrow) * D_N + ncol] = f2b(o[t][r] * inv[r]);
    }
  }
}

extern "C" void kernel_launch(void* const* d_in, const int* in_sizes, int n_in,
                              void* d_out, int out_size, void* d_ws, size_t ws_size,
                              hipStream_t stream) {
  (void)in_sizes; (void)n_in; (void)out_size; (void)ws_size;
  const float* query = (const float*)d_in[0];
  const float* key_  = (const float*)d_in[1];
  const float* value = (const float*)d_in[2];
  const int* fid  = (const int*)d_in[3];
  const int* eid  = (const int*)d_in[4];
  const int* tmid = (const int*)d_in[5];
  const int* ttid = (const int*)d_in[6];
  const int* edid = (const int*)d_in[7];
  const int* rlid = (const int*)d_in[8];
  const float* Wq = (const float*)d_in[9];  const float* bq = (const float*)d_in[10];
  const float* Wk = (const float*)d_in[11]; const float* bk = (const float*)d_in[12];
  const float* Wv = (const float*)d_in[13]; const float* bv = (const float*)d_in[14];
  const float* Wo = (const float*)d_in[15]; const float* bo = (const float*)d_in[16];

  char* ws = (char*)d_ws;
  const size_t MB = 1024 * 1024;
  // [0, 34MB): Xq/Xk/Xv (24MB) + Wqb/Wkb/Wvb (6MB) during projections;
  //            reused as BM f32 (33.6MB) afterwards.
  ushort* Xq  = (ushort*)(ws);
  ushort* Xk  = (ushort*)(ws + 8 * MB);
  ushort* Xv  = (ushort*)(ws + 16 * MB);
  ushort* Wqb = (ushort*)(ws + 24 * MB);
  ushort* Wkb = (ushort*)(ws + 26 * MB);
  ushort* Wvb = (ushort*)(ws + 28 * MB);
  float*  BM  = (float*)(ws);
  ushort* Qws = (ushort*)(ws + 34 * MB);
  ushort* Kws = (ushort*)(ws + 42 * MB);
  ushort* VTw = (ushort*)(ws + 50 * MB);
  ushort* AOw = (ushort*)(ws + 58 * MB);
  ushort* Wob = (ushort*)(ws + 66 * MB);
  uint32_t* codes = (uint32_t*)(ws + 68 * MB);
  // total ws use: 68MB + 16KB

  const int MK = B_N * S_N * D_N;
  const int WK = D_N * D_N;
  cvt3_kernel<<<dim3(MK / 1024, 3), 256, 0, stream>>>(query, key_, value, Xq, Xk, Xv);
  cvt4_kernel<<<dim3(WK / 1024, 4), 256, 0, stream>>>(Wq, Wk, Wv, Wo, Wqb, Wkb, Wvb, Wob);
  pack_codes_kernel<<<(B_N * S_N) / 256, 256, 0, stream>>>(fid, eid, tmid, ttid, edid, rlid, codes, B_N * S_N);

  gemm_qkv<<<dim3(D_N / 128, (B_N * S_N) / 128, 3), 256, 0, stream>>>(
      Xq, Xk, Xv, Wqb, Wkb, Wvb, bq, bk, bv, Qws, Kws, VTw);
  // bias matrix overwrites Xq/Xk/Xv + Wqb/Wkb/Wvb region (dead after gemm_qkv)
  bias_build<<<(B_N * S_N * S_N / 8) / 256, 256, 0, stream>>>(codes, BM);
  attn_kernel<<<dim3(S_N / 64, B_N * H_N), 256, 0, stream>>>(Qws, Kws, VTw, BM, AOw);
  gemm_o<<<dim3(D_N / 128, (B_N * S_N) / 128), 256, 0, stream>>>(AOw, Wob, bo, (float*)d_out);
}

// Round 4
// 214.812 us; speedup vs baseline: 1.1009x; 1.1009x over previous
//
#include <hip/hip_runtime.h>
#include <hip/hip_bf16.h>
#include <stdint.h>

#define B_N 2
#define S_N 2048
#define D_N 1024
#define H_N 16

using bf8    = __attribute__((ext_vector_type(8))) short;   // 8 bf16 (4 VGPRs)
using f32x4  = __attribute__((ext_vector_type(4))) float;
using f32x16 = __attribute__((ext_vector_type(16))) float;

static __device__ __forceinline__ ushort f2b(float f) {
  uint32_t u = __builtin_bit_cast(uint32_t, f);
  u += 0x7fffu + ((u >> 16) & 1u);     // RNE
  return (ushort)(u >> 16);
}

static __device__ __forceinline__ uint32_t cvtpk(float a, float b) {
  uint32_t r;
  asm("v_cvt_pk_bf16_f32 %0, %1, %2" : "=v"(r) : "v"(a), "v"(b));
  return r;   // low = a, high = b
}

typedef __attribute__((address_space(1))) const uint32_t GU32;
typedef __attribute__((address_space(3))) uint32_t LU32;
static __device__ __forceinline__ void gload16(const void* g, void* l) {
  __builtin_amdgcn_global_load_lds((GU32*)g, (LU32*)l, 16, 0, 0);
}

// ---------------- f32 -> bf16 converts (fused) ----------------
__global__ __launch_bounds__(256) void cvt3_kernel(const float* __restrict__ a, const float* __restrict__ b,
                                                   const float* __restrict__ c, ushort* __restrict__ oa,
                                                   ushort* __restrict__ ob, ushort* __restrict__ oc) {
  const float* s; ushort* d;
  if (blockIdx.y == 0) { s = a; d = oa; }
  else if (blockIdx.y == 1) { s = b; d = ob; }
  else { s = c; d = oc; }
  int i = (blockIdx.x * 256 + threadIdx.x) * 4;
  float4 v = *(const float4*)(s + i);
  ushort4 o;
  o.x = f2b(v.x); o.y = f2b(v.y); o.z = f2b(v.z); o.w = f2b(v.w);
  *(ushort4*)(d + i) = o;
}

__global__ __launch_bounds__(256) void cvt4_kernel(const float* __restrict__ a, const float* __restrict__ b,
                                                   const float* __restrict__ c, const float* __restrict__ e,
                                                   ushort* __restrict__ oa, ushort* __restrict__ ob,
                                                   ushort* __restrict__ oc, ushort* __restrict__ oe) {
  const float* s; ushort* d;
  if (blockIdx.y == 0) { s = a; d = oa; }
  else if (blockIdx.y == 1) { s = b; d = ob; }
  else if (blockIdx.y == 2) { s = c; d = oc; }
  else { s = e; d = oe; }
  int i = (blockIdx.x * 256 + threadIdx.x) * 4;
  float4 v = *(const float4*)(s + i);
  ushort4 o;
  o.x = f2b(v.x); o.y = f2b(v.y); o.z = f2b(v.z); o.w = f2b(v.w);
  *(ushort4*)(d + i) = o;
}

// ---------------- structural-bias precompute ----------------
__global__ __launch_bounds__(256) void pack_codes_kernel(
    const int* __restrict__ f, const int* __restrict__ e, const int* __restrict__ ti,
    const int* __restrict__ tt, const int* __restrict__ ed, const int* __restrict__ ro,
    uint32_t* __restrict__ codes, int n) {
  int i = blockIdx.x * 256 + threadIdx.x;
  if (i >= n) return;
  uint32_t c = ((uint32_t)f[i] & 31u) | (((uint32_t)e[i] & 63u) << 5) |
               (((uint32_t)ti[i] & 127u) << 11) | (((uint32_t)tt[i] & 7u) << 18) |
               (((uint32_t)ro[i] & 7u) << 21) |
               ((ed[i] != 0) ? (1u << 24) : 0u) | ((f[i] == 0) ? (1u << 25) : 0u);
  codes[i] = c;
}

static __device__ __forceinline__ float bias_val(uint32_t a, uint32_t b) {
  uint32_t x = a ^ b;
  uint32_t o = a | b;
  float v = (o & 0x1000000u) ? 1.5f : 0.0f;   // has_edge
  v += (x & 0x1Fu)     ? 0.0f : 1.0f;          // field
  v += (x & 0x7E0u)    ? 0.0f : 1.0f;          // entity
  v += (x & 0x3F800u)  ? 0.0f : 0.5f;          // time
  v += (x & 0x1C0000u) ? 0.0f : 0.3f;          // token_type
  v += (x & 0xE00000u) ? 0.0f : 0.5f;          // role
  return (o & 0x2000000u) ? -30000.f : v;      // pad -> big negative
}

// BM[b][i][j] f32 (symmetric), 8 elements per thread
__global__ __launch_bounds__(256) void bias_build(const uint32_t* __restrict__ codes,
                                                  float* __restrict__ BM) {
  int t = blockIdx.x * 256 + threadIdx.x;      // 0 .. B*S*S/8-1
  int j8 = (t & 255) * 8;                      // S/8 = 256
  int i  = (t >> 8) & 2047;
  int b  = t >> 19;                            // S*S/8 = 2^19
  uint32_t cq = codes[b * S_N + i];
  uint4 c0 = *(const uint4*)(codes + b * S_N + j8);
  uint4 c1 = *(const uint4*)(codes + b * S_N + j8 + 4);
  uint32_t cj[8] = {c0.x, c0.y, c0.z, c0.w, c1.x, c1.y, c1.z, c1.w};
  float o[8];
#pragma unroll
  for (int p = 0; p < 8; ++p) o[p] = bias_val(cq, cj[p]);
  *(float4*)(BM + (size_t)t * 8)     = *(const float4*)(o);
  *(float4*)(BM + (size_t)t * 8 + 4) = *(const float4*)(o + 4);
}

// ---------------- GEMM core: C[M,N] = A[M,K] @ W[N,K]^T + bias ----------------
template <int MODE>
static __device__ __forceinline__ void gemm_core(ushort* As, ushort* Bs,
    const ushort* __restrict__ A, const ushort* __restrict__ W, const float* __restrict__ bias,
    void* __restrict__ out, float scale) {
  const int tid = threadIdx.x, lane = tid & 63, wid = tid >> 6;
  const int g = lane >> 4, c = lane & 15;
  const int wm = wid >> 1, wn = wid & 1;
  const int m0 = blockIdx.y * 128, n0 = blockIdx.x * 128;

  f32x4 acc[4][4];
#pragma unroll
  for (int i = 0; i < 4; ++i)
#pragma unroll
    for (int j = 0; j < 4; ++j) acc[i][j] = (f32x4){0.f, 0.f, 0.f, 0.f};

  for (int k0 = 0; k0 < D_N; k0 += 32) {
#pragma unroll
    for (int j = 0; j < 2; ++j) {
      int idx = tid + j * 256;                  // 0..511
      int row = idx >> 2, c8 = (idx & 3) * 8;
      gload16(A + (size_t)(m0 + row) * D_N + k0 + c8, As + idx * 8);
      gload16(W + (size_t)(n0 + row) * D_N + k0 + c8, Bs + idx * 8);
    }
    __syncthreads();
    bf8 af[4], bw[4];
#pragma unroll
    for (int mi = 0; mi < 4; ++mi) af[mi] = *(const bf8*)(As + (wm * 64 + mi * 16 + c) * 32 + g * 8);
#pragma unroll
    for (int ni = 0; ni < 4; ++ni) bw[ni] = *(const bf8*)(Bs + (wn * 64 + ni * 16 + c) * 32 + g * 8);
#pragma unroll
    for (int mi = 0; mi < 4; ++mi)
#pragma unroll
      for (int ni = 0; ni < 4; ++ni)
        acc[mi][ni] = __builtin_amdgcn_mfma_f32_16x16x32_bf16(af[mi], bw[ni], acc[mi][ni], 0, 0, 0);
    __syncthreads();
  }

#pragma unroll
  for (int mi = 0; mi < 4; ++mi)
#pragma unroll
    for (int ni = 0; ni < 4; ++ni) {
      int ncol = n0 + wn * 64 + ni * 16 + c;
      float bv = bias[ncol];
      int hh = ncol >> 6, dd = ncol & 63;
      if (MODE == 2) {
        int mb = m0 + wm * 64 + mi * 16 + g * 4;
        int bb = mb >> 11, s = mb & 2047;
        ushort4 o4;
        o4.x = f2b((acc[mi][ni][0] + bv) * scale);
        o4.y = f2b((acc[mi][ni][1] + bv) * scale);
        o4.z = f2b((acc[mi][ni][2] + bv) * scale);
        o4.w = f2b((acc[mi][ni][3] + bv) * scale);
        *(ushort4*)((ushort*)out + (((size_t)bb * H_N + hh) * 64 + dd) * S_N + s) = o4;
      } else {
#pragma unroll
        for (int r = 0; r < 4; ++r) {
          int m = m0 + wm * 64 + mi * 16 + g * 4 + r;
          float v = (acc[mi][ni][r] + bv) * scale;
          if (MODE == 0) {
            int bb = m >> 11, s = m & 2047;
            ((ushort*)out)[(((size_t)bb * H_N + hh) * S_N + s) * 64 + dd] = f2b(v);
          } else {
            ((float*)out)[(size_t)m * D_N + ncol] = v;
          }
        }
      }
    }
}

__global__ __launch_bounds__(256) void gemm_qkv(
    const ushort* __restrict__ Xq, const ushort* __restrict__ Xk, const ushort* __restrict__ Xv,
    const ushort* __restrict__ Wq, const ushort* __restrict__ Wk, const ushort* __restrict__ Wv,
    const float* __restrict__ bq, const float* __restrict__ bk, const float* __restrict__ bv,
    ushort* __restrict__ Qo, ushort* __restrict__ Ko, ushort* __restrict__ Vo) {
  __shared__ __align__(16) ushort As[128 * 32];
  __shared__ __align__(16) ushort Bs[128 * 32];
  if (blockIdx.z == 0)      gemm_core<0>(As, Bs, Xq, Wq, bq, Qo, 0.125f);
  else if (blockIdx.z == 1) gemm_core<0>(As, Bs, Xk, Wk, bk, Ko, 1.0f);
  else                      gemm_core<2>(As, Bs, Xv, Wv, bv, Vo, 1.0f);
}

__global__ __launch_bounds__(256) void gemm_o(const ushort* __restrict__ A, const ushort* __restrict__ W,
                                              const float* __restrict__ bias, float* __restrict__ out) {
  __shared__ __align__(16) ushort As[128 * 32];
  __shared__ __align__(16) ushort Bs[128 * 32];
  gemm_core<1>(As, Bs, A, W, bias, out, 1.0f);
}

// ---------------- flash attention: 8-warp 32x32 swapped-QK^T, in-register softmax ----
// grid (S/256, B*H), 512 thr (8 warps x 32 q rows). Q pre-scaled by 0.125.
// Swapped QK^T: S^T = mfma(K, Q) -> score col q = lane&31 (lane-local softmax).
// Bias symmetric -> read BM[b][q][kv] rows as f32x4 straight into the accumulator init.
// P stays in registers (cvt_pk + shfl_xor(32) re-shape); defer-max THR=8.
__global__ __launch_bounds__(512, 2) void attn_kernel(const ushort* __restrict__ Qw, const ushort* __restrict__ Kw,
                                                      const ushort* __restrict__ VT, const float* __restrict__ BMf,
                                                      ushort* __restrict__ AO) {
  __shared__ __align__(16) ushort Ks[2][64 * 64];
  __shared__ __align__(16) ushort Vs[2][64 * 64];   // V^T tile: [d][kv]
  const int tid = threadIdx.x, lane = tid & 63, w = tid >> 6;
  const int l31 = lane & 31, hi = lane >> 5;
  const int bh = blockIdx.y, b = bh >> 4, h = bh & 15;
  const int q0 = blockIdx.x * 256;
  const int qg = q0 + w * 32 + l31;                 // this lane's q row

  // Q fragments (B-operand): d = ks*16 + hi*8 + j
  bf8 aq[4];
  {
    const ushort* qp = Qw + ((size_t)bh * S_N + qg) * 64;
#pragma unroll
    for (int ks = 0; ks < 4; ++ks) aq[ks] = *(const bf8*)(qp + ks * 16 + hi * 8);
  }
  const float*  Brow  = BMf + ((size_t)b * S_N + qg) * S_N;   // bias row (symmetric)
  const ushort* Kbase = Kw + (size_t)bh * (S_N * 64);
  const ushort* Vbase = VT + (size_t)bh * (64 * S_N);

  float mr = -1e30f, lr = 0.f;
  f32x16 o0, o1;
#pragma unroll
  for (int r = 0; r < 16; ++r) { o0[r] = 0.f; o1[r] = 0.f; }

  const int CROW0[16] = {0,1,2,3, 8,9,10,11, 16,17,18,19, 24,25,26,27};

  auto STAGE = [&](int bi, int kv0) {
    int row = tid >> 3, slot = tid & 7;
    int sl = ((slot ^ (row & 7)) * 8);
    gload16(Kbase + (size_t)(kv0 + row) * 64 + sl, &Ks[bi][tid * 8]);
    gload16(Vbase + (size_t)row * S_N + kv0 + sl, &Vs[bi][tid * 8]);
  };
  auto BLOAD = [&](float* bb, int kv0) {
#pragma unroll
    for (int t = 0; t < 2; ++t)
#pragma unroll
      for (int g = 0; g < 4; ++g) {
        float4 v = *(const float4*)(Brow + kv0 + t * 32 + g * 8 + 4 * hi);
        bb[t * 16 + g * 4 + 0] = v.x; bb[t * 16 + g * 4 + 1] = v.y;
        bb[t * 16 + g * 4 + 2] = v.z; bb[t * 16 + g * 4 + 3] = v.w;
      }
  };

  auto TILE = [&](int bi, const float* bb) {
    // scores init = bias (s[t][r] covers kv = t*32 + (r&3) + 8*(r>>2) + 4*hi)
    f32x16 s0, s1;
#pragma unroll
    for (int r = 0; r < 16; ++r) { s0[r] = bb[r]; s1[r] = bb[16 + r]; }
    // QK^T (swapped): A = K rows, B = Q
    const ushort* Kb = &Ks[bi][0];
    __builtin_amdgcn_s_setprio(1);
#pragma unroll
    for (int ks = 0; ks < 4; ++ks) {
      int sl0 = ((ks * 2 + hi) ^ (l31 & 7)) * 8;
      bf8 k0 = *(const bf8*)(Kb + l31 * 64 + sl0);
      bf8 k1 = *(const bf8*)(Kb + (32 + l31) * 64 + sl0);
      s0 = __builtin_amdgcn_mfma_f32_32x32x16_bf16(k0, aq[ks], s0, 0, 0, 0);
      s1 = __builtin_amdgcn_mfma_f32_32x32x16_bf16(k1, aq[ks], s1, 0, 0, 0);
    }
    __builtin_amdgcn_s_setprio(0);

    // row max (q = lane&31 is lane-local; partner holds other half of kv)
    float mt = s0[0];
#pragma unroll
    for (int r = 1; r < 16; ++r) mt = fmaxf(mt, s0[r]);
#pragma unroll
    for (int r = 0; r < 16; ++r) mt = fmaxf(mt, s1[r]);
    mt = fmaxf(mt, __shfl_xor(mt, 32));

    if (__any(mt > mr + 8.0f)) {          // defer-max (T13): rescale only when needed
      float mn = fmaxf(mr, mt);
      float sc = __expf(mr - mn);
      lr *= sc;
#pragma unroll
      for (int r = 0; r < 16; ++r) {
        float scr = __shfl(sc, CROW0[r] + 4 * hi);
        o0[r] *= scr; o1[r] *= scr;
      }
      mr = mn;
    }
    float sum = 0.f;
#pragma unroll
    for (int r = 0; r < 16; ++r) { s0[r] = __expf(s0[r] - mr); sum += s0[r]; }
#pragma unroll
    for (int r = 0; r < 16; ++r) { s1[r] = __expf(s1[r] - mr); sum += s1[r]; }
    sum += __shfl_xor(sum, 32);
    lr += sum;

    // P (f32, S^T layout) -> PV A-fragments via cvt_pk + partner exchange
    bf8 pa[4];
#pragma unroll
    for (int t = 0; t < 2; ++t) {
      uint32_t wv[4][2];
#pragma unroll
      for (int g = 0; g < 4; ++g) {
        const float* sp = (t == 0) ? (const float*)&s0 : (const float*)&s1;
        wv[g][0] = cvtpk(sp[g * 4 + 0], sp[g * 4 + 1]);
        wv[g][1] = cvtpk(sp[g * 4 + 2], sp[g * 4 + 3]);
      }
#pragma unroll
      for (int pr = 0; pr < 2; ++pr) {      // pair (g0,g1)->ks 2t, (g2,g3)->ks 2t+1
        uint32_t x0 = hi ? wv[2 * pr][0] : wv[2 * pr + 1][0];
        uint32_t x1 = hi ? wv[2 * pr][1] : wv[2 * pr + 1][1];
        uint32_t r0 = (uint32_t)__shfl_xor((int)x0, 32);
        uint32_t r1 = (uint32_t)__shfl_xor((int)x1, 32);
        uint4 pw;
        pw.x = hi ? r0 : wv[2 * pr][0];
        pw.y = hi ? r1 : wv[2 * pr][1];
        pw.z = hi ? wv[2 * pr + 1][0] : r0;
        pw.w = hi ? wv[2 * pr + 1][1] : r1;
        pa[t * 2 + pr] = __builtin_bit_cast(bf8, pw);
      }
    }

    // PV: O[q][d] += P[q][kv] V[kv][d]; V^T tile rows = d
    const ushort* Vb = &Vs[bi][0];
    __builtin_amdgcn_s_setprio(1);
#pragma unroll
    for (int ks = 0; ks < 4; ++ks) {
      int sl0 = ((ks * 2 + hi) ^ (l31 & 7)) * 8;
      bf8 v0 = *(const bf8*)(Vb + l31 * 64 + sl0);
      bf8 v1 = *(const bf8*)(Vb + (32 + l31) * 64 + sl0);
      o0 = __builtin_amdgcn_mfma_f32_32x32x16_bf16(pa[ks], v0, o0, 0, 0, 0);
      o1 = __builtin_amdgcn_mfma_f32_32x32x16_bf16(pa[ks], v1, o1, 0, 0, 0);
    }
    __builtin_amdgcn_s_setprio(0);
  };

  float biasA[32], biasB[32];
  STAGE(0, 0);  BLOAD(biasA, 0);
  STAGE(1, 64); BLOAD(biasB, 64);

#pragma unroll 1
  for (int t = 0; t < 32; t += 2) {
    asm volatile("s_waitcnt vmcnt(10)" ::: "memory");   // stage(t)+bias(t) drained
    __builtin_amdgcn_s_barrier();
    __builtin_amdgcn_sched_barrier(0);
    TILE(0, biasA);
    __builtin_amdgcn_s_barrier();                       // all warps done reading buf0
    __builtin_amdgcn_sched_barrier(0);
    if (t + 2 < 32) { STAGE(0, (t + 2) * 64); BLOAD(biasA, (t + 2) * 64); }

    if (t + 2 < 32) asm volatile("s_waitcnt vmcnt(10)" ::: "memory");
    else            asm volatile("s_waitcnt vmcnt(0)" ::: "memory");
    __builtin_amdgcn_s_barrier();
    __builtin_amdgcn_sched_barrier(0);
    TILE(1, biasB);
    __builtin_amdgcn_s_barrier();
    __builtin_amdgcn_sched_barrier(0);
    if (t + 3 < 32) { STAGE(1, (t + 3) * 64); BLOAD(biasB, (t + 3) * 64); }
  }

  // epilogue: O / l  (broadcast per-q inverse into the C/D row layout)
  float inv = 1.0f / lr;
#pragma unroll
  for (int r = 0; r < 16; ++r) {
    float ivr = __shfl(inv, CROW0[r] + 4 * hi);
    int q = q0 + w * 32 + CROW0[r] + 4 * hi;
    size_t base = ((size_t)b * S_N + q) * D_N + h * 64 + l31;
    AO[base]      = f2b(o0[r] * ivr);
    AO[base + 32] = f2b(o1[r] * ivr);
  }
}

extern "C" void kernel_launch(void* const* d_in, const int* in_sizes, int n_in,
                              void* d_out, int out_size, void* d_ws, size_t ws_size,
                              hipStream_t stream) {
  (void)in_sizes; (void)n_in; (void)out_size; (void)ws_size;
  const float* query = (const float*)d_in[0];
  const float* key_  = (const float*)d_in[1];
  const float* value = (const float*)d_in[2];
  const int* fid  = (const int*)d_in[3];
  const int* eid  = (const int*)d_in[4];
  const int* tmid = (const int*)d_in[5];
  const int* ttid = (const int*)d_in[6];
  const int* edid = (const int*)d_in[7];
  const int* rlid = (const int*)d_in[8];
  const float* Wq = (const float*)d_in[9];  const float* bq = (const float*)d_in[10];
  const float* Wk = (const float*)d_in[11]; const float* bk = (const float*)d_in[12];
  const float* Wv = (const float*)d_in[13]; const float* bv = (const float*)d_in[14];
  const float* Wo = (const float*)d_in[15]; const float* bo = (const float*)d_in[16];

  char* ws = (char*)d_ws;
  const size_t MB = 1024 * 1024;
  // [0, 34MB): Xq/Xk/Xv (24MB) + Wqb/Wkb/Wvb (6MB) during projections;
  //            reused as BM f32 (33.6MB) afterwards.
  ushort* Xq  = (ushort*)(ws);
  ushort* Xk  = (ushort*)(ws + 8 * MB);
  ushort* Xv  = (ushort*)(ws + 16 * MB);
  ushort* Wqb = (ushort*)(ws + 24 * MB);
  ushort* Wkb = (ushort*)(ws + 26 * MB);
  ushort* Wvb = (ushort*)(ws + 28 * MB);
  float*  BM  = (float*)(ws);
  ushort* Qws = (ushort*)(ws + 34 * MB);
  ushort* Kws = (ushort*)(ws + 42 * MB);
  ushort* VTw = (ushort*)(ws + 50 * MB);
  ushort* AOw = (ushort*)(ws + 58 * MB);
  ushort* Wob = (ushort*)(ws + 66 * MB);
  uint32_t* codes = (uint32_t*)(ws + 68 * MB);
  // total ws use: 68MB + 16KB

  const int MK = B_N * S_N * D_N;
  const int WK = D_N * D_N;
  cvt3_kernel<<<dim3(MK / 1024, 3), 256, 0, stream>>>(query, key_, value, Xq, Xk, Xv);
  cvt4_kernel<<<dim3(WK / 1024, 4), 256, 0, stream>>>(Wq, Wk, Wv, Wo, Wqb, Wkb, Wvb, Wob);
  pack_codes_kernel<<<(B_N * S_N) / 256, 256, 0, stream>>>(fid, eid, tmid, ttid, edid, rlid, codes, B_N * S_N);

  gemm_qkv<<<dim3(D_N / 128, (B_N * S_N) / 128, 3), 256, 0, stream>>>(
      Xq, Xk, Xv, Wqb, Wkb, Wvb, bq, bk, bv, Qws, Kws, VTw);
  // bias matrix overwrites Xq/Xk/Xv + Wqb/Wkb/Wvb region (dead after gemm_qkv)
  bias_build<<<(B_N * S_N * S_N / 8) / 256, 256, 0, stream>>>(codes, BM);
  attn_kernel<<<dim3(S_N / 256, B_N * H_N), 512, 0, stream>>>(Qws, Kws, VTw, BM, AOw);
  gemm_o<<<dim3(D_N / 128, (B_N * S_N) / 128), 256, 0, stream>>>(AOw, Wob, bo, (float*)d_out);
}